// Round 2
// baseline (473.762 us; speedup 1.0000x reference)
//
#include <hip/hip_runtime.h>
#include <stdint.h>

typedef short short8 __attribute__((ext_vector_type(8)));
typedef float f32x4 __attribute__((ext_vector_type(4)));
typedef unsigned short u16;
typedef unsigned int u32;

struct alignas(8) U16x4 { u16 x, y, z, w; };

__device__ __forceinline__ u16 f2bf(float f) {
  u32 u = __float_as_uint(f);
  u += 0x7fffu + ((u >> 16) & 1u);
  return (u16)(u >> 16);
}
__device__ __forceinline__ float bf2f(u16 v) {
  return __uint_as_float(((u32)v) << 16);
}

__device__ __forceinline__ void gld_lds16(const u16* g, u16* l) {
  __builtin_amdgcn_global_load_lds((const __attribute__((address_space(1))) u32*)g,
                                   (__attribute__((address_space(3))) u32*)l,
                                   16, 0, 0);
}

__device__ __forceinline__ void mfma16x16x32(f32x4& c, short8 a, short8 b) {
  asm("v_mfma_f32_16x16x32_bf16 %0, %1, %2, %0" : "+v"(c) : "v"(a), "v"(b));
}

// ---------------------------------------------------------------------------
// Batched C = A * B^T  (A: [M,K] row-major, Bt: [N,K] row-major), BK=128.
// EPI 0: bf16 out, none
// EPI 6: bf16 out, + v1[b*512+row]*v2[col] + v3[row]*v4[b*512+col]
// EPI 4: f32 out,  acc*v1[row] + v2[b*512+row] + xres[b][row][col]
// M, N divisible by 128; K divisible by 128.
// ---------------------------------------------------------------------------
template<int EPI>
__global__ void gemm_abt(const u16* __restrict__ A, int64_t Abs,
                         const u16* __restrict__ Bt, int64_t Bbs,
                         void* __restrict__ Cptr, int64_t Cbs,
                         int M, int N, int K,
                         const float* __restrict__ v1,
                         const float* __restrict__ v2,
                         const float* __restrict__ v3,
                         const float* __restrict__ v4,
                         const float* __restrict__ xres) {
  constexpr int BM = 128, BN = 128, BK = 128;
  __shared__ u16 As[BM * BK];
  __shared__ u16 Bs[BN * BK];

  const int b = blockIdx.z;
  const u16* Ab = A + (int64_t)b * Abs;
  const u16* Bb = Bt + (int64_t)b * Bbs;
  const int brow = blockIdx.y * BM, bcol = blockIdx.x * BN;
  const int tid = threadIdx.x, lane = tid & 63, w = tid >> 6;
  const int wr = w >> 1, wc = w & 1;

  f32x4 acc[4][4] = {};

  // staging: thread t -> row (t>>4)+i*16, col chunk (t&15)*8 elems; LDS linear.
  const int sr = tid >> 4;
  const int sc = (tid & 15) * 8;
  u16* lA = &As[sr * BK + sc];
  u16* lB = &Bs[sr * BK + sc];
  const u16* gA = Ab + (int64_t)(brow + sr) * K + sc;
  const u16* gB = Bb + (int64_t)(bcol + sr) * K + sc;

  const int la16 = lane & 15;
  const int kg = (lane >> 4) * 8;

  for (int k0 = 0; k0 < K; k0 += BK) {
#pragma unroll
    for (int i = 0; i < 8; ++i) gld_lds16(gA + (int64_t)i * 16 * K + k0, lA + i * 16 * BK);
#pragma unroll
    for (int i = 0; i < 8; ++i) gld_lds16(gB + (int64_t)i * 16 * K + k0, lB + i * 16 * BK);
    __syncthreads();
#pragma unroll
    for (int kk = 0; kk < 4; ++kk) {
      short8 af[4], bf[4];
#pragma unroll
      for (int m = 0; m < 4; ++m)
        af[m] = *(const short8*)&As[(wr * 64 + m * 16 + la16) * BK + kk * 32 + kg];
#pragma unroll
      for (int n = 0; n < 4; ++n)
        bf[n] = *(const short8*)&Bs[(wc * 64 + n * 16 + la16) * BK + kk * 32 + kg];
#pragma unroll
      for (int m = 0; m < 4; ++m)
#pragma unroll
        for (int n = 0; n < 4; ++n)
          mfma16x16x32(acc[m][n], af[m], bf[n]);
    }
    __syncthreads();
  }
  asm volatile("s_nop 7\n\ts_nop 7");  // MFMA->VALU hazard guard (asm mfma)

  // D frag (m,n): row = brow+wr*64+m*16+(lane>>4)*4+r, col = bcol+wc*64+n*16+(lane&15)
  const int r0 = brow + wr * 64 + (lane >> 4) * 4;
  const int c0 = bcol + wc * 64 + la16;
  const int64_t b512 = (int64_t)b * 512;

  if (EPI == 4) {
    float* Cb = (float*)Cptr + (int64_t)b * Cbs;
    const float* xb = xres + (int64_t)b * Cbs;
#pragma unroll
    for (int m = 0; m < 4; ++m) {
#pragma unroll
      for (int r = 0; r < 4; ++r) {
        const int row = r0 + m * 16 + r;
        const float scl = v1[row], shf = v2[b512 + row];
#pragma unroll
        for (int n = 0; n < 4; ++n) {
          const int col = c0 + n * 16;
          Cb[(int64_t)row * N + col] = acc[m][n][r] * scl + shf + xb[(int64_t)row * N + col];
        }
      }
    }
  } else {
    u16* Cb = (u16*)Cptr + (int64_t)b * Cbs;
#pragma unroll
    for (int m = 0; m < 4; ++m) {
#pragma unroll
      for (int r = 0; r < 4; ++r) {
        const int row = r0 + m * 16 + r;
        float a1 = 0.f, a3 = 0.f;
        if (EPI == 6) { a1 = v1[b512 + row]; a3 = v3[row]; }
#pragma unroll
        for (int n = 0; n < 4; ++n) {
          const int col = c0 + n * 16;
          float v = acc[m][n][r];
          if (EPI == 6) v += a1 * v2[col] + a3 * v4[b512 + col];
          Cb[(int64_t)row * N + col] = f2bf(v);
        }
      }
    }
  }
}

// ---- f32 row -> bf16 row + row-sum.  One block (256 thr) per row of 1152. ----
__global__ void cvt_row(const float* __restrict__ in, u16* __restrict__ out,
                        float* __restrict__ rowsum) {
  const int64_t row = blockIdx.x;
  const float4* ib = (const float4*)(in + row * 1152);
  U16x4* ob = (U16x4*)(out + row * 1152);
  float s = 0.f;
  for (int i = threadIdx.x; i < 288; i += 256) {
    float4 v = ib[i];
    s += v.x + v.y + v.z + v.w;
    U16x4 o = {f2bf(v.x), f2bf(v.y), f2bf(v.z), f2bf(v.w)};
    ob[i] = o;
  }
  for (int off = 32; off; off >>= 1) s += __shfl_down(s, off);
  __shared__ float red[4];
  if ((threadIdx.x & 63) == 0) red[threadIdx.x >> 6] = s;
  __syncthreads();
  if (threadIdx.x == 0) rowsum[row] = red[0] + red[1] + red[2] + red[3];
}

// ---- bf16 [C][N] -> bf16 [N][C] per batch, 32x32 tiles ----
__global__ void transpose_bf(const u16* __restrict__ in, u16* __restrict__ out,
                             int C, int N) {
  __shared__ u16 t[32][36];
  const int b = blockIdx.z;
  const u16* ib = in + (int64_t)b * C * N;
  u16* ob = out + (int64_t)b * C * N;
  const int n0 = blockIdx.x * 32, c0 = blockIdx.y * 32;
  const int tr = threadIdx.x >> 3, tc = (threadIdx.x & 7) * 4;
  U16x4 v = *(const U16x4*)&ib[(int64_t)(c0 + tr) * N + n0 + tc];
  t[tr][tc] = v.x; t[tr][tc + 1] = v.y; t[tr][tc + 2] = v.z; t[tr][tc + 3] = v.w;
  __syncthreads();
  U16x4 o = {t[tc][tr], t[tc + 1][tr], t[tc + 2][tr], t[tc + 3][tr]};
  *(U16x4*)&ob[(int64_t)(n0 + tr) * C + c0 + tc] = o;
}

// ---- f32 [C][N] -> bf16 [N][C] (weights; single batch) ----
__global__ void transpose_cvt(const float* __restrict__ in, u16* __restrict__ out,
                              int C, int N) {
  __shared__ float t[32][33];
  const int n0 = blockIdx.x * 32, c0 = blockIdx.y * 32;
  const int tr = threadIdx.x >> 3, tc = (threadIdx.x & 7) * 4;
  const float4 v = *(const float4*)&in[(int64_t)(c0 + tr) * N + n0 + tc];
  t[tr][tc] = v.x; t[tr][tc + 1] = v.y; t[tr][tc + 2] = v.z; t[tr][tc + 3] = v.w;
  __syncthreads();
  U16x4 o;
  o.x = f2bf(t[tc][tr]); o.y = f2bf(t[tc + 1][tr]);
  o.z = f2bf(t[tc + 2][tr]); o.w = f2bf(t[tc + 3][tr]);
  *(U16x4*)&out[(int64_t)(n0 + tr) * C + c0 + tc] = o;
}

// ---- f32 -> bf16 elementwise ----
__global__ void cvt_kernel(const float* __restrict__ in, u16* __restrict__ out, int n4) {
  const int i = blockIdx.x * 256 + threadIdx.x;
  if (i < n4) {
    const float4 v = ((const float4*)in)[i];
    U16x4 o = {f2bf(v.x), f2bf(v.y), f2bf(v.z), f2bf(v.w)};
    ((U16x4*)out)[i] = o;
  }
}

// ---- batch-independent small vectors + BN prep.  grid 33 x 64 thr ----
__global__ void k_statics(const float* __restrict__ Wp, const float* __restrict__ Ww,
                          const float* __restrict__ Wg,
                          const float* __restrict__ bg, const float* __restrict__ bt,
                          const float* __restrict__ bp, const float* __restrict__ bw,
                          const float* __restrict__ gamma, const float* __restrict__ beta,
                          const float* __restrict__ mean, const float* __restrict__ var,
                          float* __restrict__ h1, float* __restrict__ w1,
                          float* __restrict__ c2, float* __restrict__ s2,
                          float* __restrict__ scale, float* __restrict__ sc2,
                          float* __restrict__ shift0) {
  const int gid = blockIdx.x * 64 + threadIdx.x;
  if (gid < 512) {                    // h1[j] = sum_b' Wp[b',j]*bg[b']
    float s = 0;
    for (int k = 0; k < 512; ++k) s += Wp[k * 512 + gid] * bg[k];
    h1[gid] = s;
  } else if (gid < 1024) {            // w1[c] = sum_a Ww[c,a]*bt[a]
    const int c = gid - 512;
    float s = 0;
    for (int k = 0; k < 512; ++k) s += Ww[(int64_t)c * 512 + k] * bt[k];
    w1[c] = s;
  } else if (gid < 1536) {            // c2[e] = sum_b' Wg[b',e]*bp[b']
    const int e = gid - 1024;
    float s = 0;
    for (int k = 0; k < 512; ++k) s += Wg[k * 512 + e] * bp[k];
    c2[e] = s;
  } else if (gid < 2048) {            // BN prep
    const int c = gid - 1536;
    const float sc = gamma[c] * rsqrtf(var[c] + 1e-5f);
    scale[c] = sc;
    sc2[c] = sc * (1.0f / 512.0f);
    shift0[c] = (bw[c] - mean[c]) * sc + beta[c];
  } else {                            // one wave: s2 = bp . bg
    const int l = gid - 2048;
    float p = 0;
    for (int k = l; k < 512; k += 64) p += bp[k] * bg[k];
    for (int off = 32; off; off >>= 1) p += __shfl_down(p, off);
    if (l == 0) s2[0] = p;
  }
}

// ---- per-batch: sigphi = Wp*rxh ; tau2 = Wt*rx + 1152*bt.  grid 32 x 512 ----
__global__ void k_sigma_tau(const float* __restrict__ Wp, const float* __restrict__ Wt,
                            const float* __restrict__ bt,
                            const float* __restrict__ rx, const float* __restrict__ rxh,
                            float* __restrict__ sigphi, float* __restrict__ tau2) {
  __shared__ float rxl[512], rxhl[512];
  const int bb = blockIdx.x, t = threadIdx.x;
  rxl[t] = rx[bb * 512 + t];
  rxhl[t] = rxh[bb * 512 + t];
  __syncthreads();
  float sp = 0, ta = 0;
  for (int d = 0; d < 512; ++d) {
    sp += Wp[(int64_t)t * 512 + d] * rxhl[d];
    ta += Wt[(int64_t)t * 512 + d] * rxl[d];
  }
  sigphi[bb * 512 + t] = sp;
  tau2[bb * 512 + t] = ta + 1152.0f * bt[t];
}

// ---- per-batch: c1 = Wg^T*sigphi ; w2 = Ww*tau2 ; s1 = sigphi.bg. grid 32x512 ----
__global__ void k_c1w2(const float* __restrict__ Wg, const float* __restrict__ Ww,
                       const float* __restrict__ bg,
                       const float* __restrict__ sigphi, const float* __restrict__ tau2,
                       float* __restrict__ c1, float* __restrict__ w2,
                       float* __restrict__ s1) {
  __shared__ float spl[512], tal[512];
  __shared__ float red[8];
  const int bb = blockIdx.x, t = threadIdx.x;
  spl[t] = sigphi[bb * 512 + t];
  tal[t] = tau2[bb * 512 + t];
  __syncthreads();
  float c = 0, wv = 0;
  for (int k = 0; k < 512; ++k) {
    c += Wg[k * 512 + t] * spl[k];
    wv += Ww[(int64_t)t * 512 + k] * tal[k];
  }
  c1[bb * 512 + t] = c;
  w2[bb * 512 + t] = wv;
  float p = spl[t] * bg[t];
  for (int off = 32; off; off >>= 1) p += __shfl_down(p, off);
  if ((t & 63) == 0) red[t >> 6] = p;
  __syncthreads();
  if (t == 0) {
    float s = 0;
    for (int i = 0; i < 8; ++i) s += red[i];
    s1[bb] = s;
  }
}

// ---- per-batch u/v chain -> shiftv.  grid 32 x 512 ----
__global__ void k_uv(const u16* __restrict__ MT, const float* __restrict__ h1,
                     const float* __restrict__ Wt, const float* __restrict__ Ww,
                     const float* __restrict__ bt, const float* __restrict__ tau2,
                     const float* __restrict__ s1, const float* __restrict__ s2,
                     const float* __restrict__ scale, const float* __restrict__ shift0,
                     float* __restrict__ shiftv) {
  __shared__ float h1l[512], m1l[512], ul[512];
  const int bb = blockIdx.x, t = threadIdx.x;
  h1l[t] = h1[t];
  __syncthreads();
  const u16* Mb = MT + (int64_t)bb * 262144;
  float acc = 0;
  for (int j = 0; j < 512; ++j) acc += bf2f(Mb[j * 512 + t]) * h1l[j];
  m1l[t] = acc;
  __syncthreads();
  float u = 0;
  for (int d = 0; d < 512; ++d) u += Wt[(int64_t)t * 512 + d] * m1l[d];
  u = (u + bt[t] * s1[bb] + tau2[bb * 512 + t] * s2[0]) * (1.0f / 512.0f);
  ul[t] = u;
  __syncthreads();
  float v = 0;
  for (int a = 0; a < 512; ++a) v += Ww[(int64_t)t * 512 + a] * ul[a];
  shiftv[bb * 512 + t] = v * scale[t] + shift0[t];
}

extern "C" void kernel_launch(void* const* d_in, const int* in_sizes, int n_in,
                              void* d_out, int out_size, void* d_ws, size_t ws_size,
                              hipStream_t stream) {
  const float* x     = (const float*)d_in[0];
  const float* x_h   = (const float*)d_in[1];
  const float* Wg    = (const float*)d_in[2];
  const float* bg    = (const float*)d_in[3];
  const float* Wt    = (const float*)d_in[4];
  const float* bt    = (const float*)d_in[5];
  const float* Wp    = (const float*)d_in[6];
  const float* bp    = (const float*)d_in[7];
  const float* Ww    = (const float*)d_in[8];
  const float* bw    = (const float*)d_in[9];
  const float* gamma = (const float*)d_in[10];
  const float* beta  = (const float*)d_in[11];
  const float* rmean = (const float*)d_in[12];
  const float* rvar  = (const float*)d_in[13];
  float* out = (float*)d_out;

  const int Bsz = 32, D = 512, N = 1152;
  const int64_t DN = (int64_t)D * N;   // 589824
  const int64_t DD = (int64_t)D * D;   // 262144

  char* ws = (char*)d_ws;
  const size_t KB = 1024, MB = 1048576;
  u16* WtT  = (u16*)(ws + 0);
  u16* WpT  = (u16*)(ws + 512 * KB);
  u16* WgT  = (u16*)(ws + 1 * MB);
  u16* WwB  = (u16*)(ws + 1 * MB + 512 * KB);
  u16* WaB  = (u16*)(ws + 2 * MB);
  u16* WbTB = (u16*)(ws + 2 * MB + 512 * KB);
  float* rx     = (float*)(ws + 3 * MB);
  float* rxh    = (float*)(ws + 3 * MB + 64 * KB);
  float* sigphi = (float*)(ws + 3 * MB + 128 * KB);
  float* tau2   = (float*)(ws + 3 * MB + 192 * KB);
  float* c1     = (float*)(ws + 3 * MB + 256 * KB);
  float* w2     = (float*)(ws + 3 * MB + 320 * KB);
  float* shiftv = (float*)(ws + 3 * MB + 384 * KB);
  float* h1     = (float*)(ws + 3 * MB + 448 * KB);
  float* w1     = (float*)(ws + 3 * MB + 450 * KB);
  float* c2     = (float*)(ws + 3 * MB + 452 * KB);
  float* scale  = (float*)(ws + 3 * MB + 454 * KB);
  float* sc2    = (float*)(ws + 3 * MB + 456 * KB);
  float* shift0 = (float*)(ws + 3 * MB + 458 * KB);
  float* s1     = (float*)(ws + 3 * MB + 460 * KB);
  float* s2     = (float*)(ws + 3 * MB + 462 * KB);
  const size_t SLOT = (size_t)Bsz * DN * sizeof(u16);   // 37,748,736
  u16* xB  = (u16*)(ws + 4 * MB);
  u16* xhB = (u16*)(ws + 4 * MB + SLOT);
  u16* xhT = (u16*)(ws + 4 * MB + 2 * SLOT);
  u16* SD1 = (u16*)(ws + 4 * MB + 3 * SLOT);               // MT -> Q
  u16* SD2 = (u16*)(ws + 4 * MB + 3 * SLOT + 32 * MB);     // R
  // total ws use ~151 MB

  // --- prep ---
  cvt_row<<<dim3(Bsz * D), 256, 0, stream>>>(x, xB, rx);
  cvt_row<<<dim3(Bsz * D), 256, 0, stream>>>(x_h, xhB, rxh);
  transpose_bf<<<dim3(N / 32, D / 32, Bsz), 256, 0, stream>>>(xhB, xhT, D, N);
  transpose_cvt<<<dim3(16, 16, 1), 256, 0, stream>>>(Wt, WtT, D, D);
  transpose_cvt<<<dim3(16, 16, 1), 256, 0, stream>>>(Wp, WpT, D, D);
  transpose_cvt<<<dim3(16, 16, 1), 256, 0, stream>>>(Wg, WgT, D, D);
  cvt_kernel<<<dim3((D * D / 4 + 255) / 256), 256, 0, stream>>>(Ww, WwB, D * D / 4);
  k_statics<<<dim3(33), 64, 0, stream>>>(Wp, Ww, Wg, bg, bt, bp, bw, gamma, beta,
                                         rmean, rvar, h1, w1, c2, s2, scale, sc2, shift0);
  // Wa = Ww*Wt ; WbT[e,j] = sum_b' Wg[b',e]*Wp[b',j]
  gemm_abt<0><<<dim3(4, 4, 1), 256, 0, stream>>>(
      WwB, 0, WtT, 0, WaB, 0, D, D, D, nullptr, nullptr, nullptr, nullptr, nullptr);
  gemm_abt<0><<<dim3(4, 4, 1), 256, 0, stream>>>(
      WgT, 0, WpT, 0, WbTB, 0, D, D, D, nullptr, nullptr, nullptr, nullptr, nullptr);
  k_sigma_tau<<<dim3(Bsz), 512, 0, stream>>>(Wp, Wt, bt, rx, rxh, sigphi, tau2);
  k_c1w2<<<dim3(Bsz), 512, 0, stream>>>(Wg, Ww, bg, sigphi, tau2, c1, w2, s1);

  // --- main chain ---
  // G1: MT[j,i] = sum_n x_h[j,n] x[i,n]
  gemm_abt<0><<<dim3(4, 4, Bsz), 256, 0, stream>>>(
      xhB, DN, xB, DN, SD1, DD, D, D, N, nullptr, nullptr, nullptr, nullptr, nullptr);
  // shiftv (reads MT)
  k_uv<<<dim3(Bsz), 512, 0, stream>>>(SD1, h1, Wt, Ww, bt, tau2, s1, s2,
                                      scale, shift0, shiftv);
  // G2: R[p,j] = sum_i Wa[p,i] MT[j,i]
  gemm_abt<0><<<dim3(4, 4, Bsz), 256, 0, stream>>>(
      WaB, 0, SD1, DD, SD2, DD, D, D, D, nullptr, nullptr, nullptr, nullptr, nullptr);
  // G3: Q[p,e] = sum_j R[p,j] WbT[e,j]  + rank-2 bias correction
  gemm_abt<6><<<dim3(4, 4, Bsz), 256, 0, stream>>>(
      SD2, DD, WbTB, 0, SD1, DD, D, D, D, w2, c2, w1, c1, nullptr);
  // G6: out[c,n] = sc2[c]*sum_e Q[c,e] xhT[n,e] + shiftv[b,c] + x[b,c,n]
  gemm_abt<4><<<dim3(N / 128, 4, Bsz), 256, 0, stream>>>(
      SD1, DD, xhT, DN, out, DN, D, N, D, sc2, shiftv, nullptr, nullptr, x);
}

// Round 3
// 353.164 us; speedup vs baseline: 1.3415x; 1.3415x over previous
//
#include <hip/hip_runtime.h>
#include <stdint.h>

typedef short short8 __attribute__((ext_vector_type(8)));
typedef float f32x4 __attribute__((ext_vector_type(4)));
typedef unsigned short u16;
typedef unsigned int u32;

struct alignas(8) U16x4 { u16 x, y, z, w; };

__device__ __forceinline__ u16 f2bf(float f) {
  u32 u = __float_as_uint(f);
  u += 0x7fffu + ((u >> 16) & 1u);
  return (u16)(u >> 16);
}
__device__ __forceinline__ float bf2f(u16 v) {
  return __uint_as_float(((u32)v) << 16);
}

__device__ __forceinline__ void gld_lds16(const u16* g, u16* l) {
  __builtin_amdgcn_global_load_lds((const __attribute__((address_space(1))) u32*)g,
                                   (__attribute__((address_space(3))) u32*)l,
                                   16, 0, 0);
}

__device__ __forceinline__ void mfma16x16x32(f32x4& c, short8 a, short8 b) {
  asm("v_mfma_f32_16x16x32_bf16 %0, %1, %2, %0" : "+v"(c) : "v"(a), "v"(b));
}

// ---------------------------------------------------------------------------
// Batched C = A * B^T (A:[M,K] rm, Bt:[N,K] rm). BK=64, double-buffered LDS,
// prefetch-ahead: issue next tile's global_load_lds BEFORE computing current,
// single barrier per K-iter (its implicit vmcnt(0) drain lands after MFMA).
// EPI 0: bf16 out; EPI 6: bf16 + v1[b512+row]*v2[col] + v3[row]*v4[b512+col];
// EPI 4: f32 out, acc*v1[row] + v2[b512+row] + xres[b][row][col]
// ---------------------------------------------------------------------------
template<int EPI>
__global__ void gemm_abt(const u16* __restrict__ A, int64_t Abs,
                         const u16* __restrict__ Bt, int64_t Bbs,
                         void* __restrict__ Cptr, int64_t Cbs,
                         int M, int N, int K,
                         const float* __restrict__ v1,
                         const float* __restrict__ v2,
                         const float* __restrict__ v3,
                         const float* __restrict__ v4,
                         const float* __restrict__ xres) {
  constexpr int BM = 128, BN = 128, BK = 64;
  __shared__ u16 As[2][BM * BK];
  __shared__ u16 Bs[2][BN * BK];

  const int b = blockIdx.z;
  const u16* Ab = A + (int64_t)b * Abs;
  const u16* Bb = Bt + (int64_t)b * Bbs;
  const int brow = blockIdx.y * BM, bcol = blockIdx.x * BN;
  const int tid = threadIdx.x, lane = tid & 63, w = tid >> 6;
  const int wr = w >> 1, wc = w & 1;

  f32x4 acc[4][4] = {};

  // staging: thread t -> row (t>>3)+i*32, col chunk (t&7)*8; LDS linear
  // (wave-uniform base + lane*16B as required by global_load_lds).
  const int sr = tid >> 3;
  const int sc = (tid & 7) * 8;
  u16* lA = &As[0][sr * BK + sc];
  u16* lB = &Bs[0][sr * BK + sc];
  const u16* gA = Ab + (int64_t)(brow + sr) * K + sc;
  const u16* gB = Bb + (int64_t)(bcol + sr) * K + sc;

  const int la16 = lane & 15;
  const int kg = (lane >> 4) * 8;
  const int nt = K / BK;

  // prologue: stage tile 0 into buf 0
#pragma unroll
  for (int i = 0; i < 4; ++i) gld_lds16(gA + (int64_t)i * 32 * K, lA + i * 32 * BK);
#pragma unroll
  for (int i = 0; i < 4; ++i) gld_lds16(gB + (int64_t)i * 32 * K, lB + i * 32 * BK);
  __syncthreads();  // compiler emits vmcnt(0) before s_barrier

  int cur = 0;
  for (int t = 0; t < nt; ++t) {
    if (t + 1 < nt) {  // issue next-tile stage FIRST (flies under MFMA)
      const int nb = cur ^ 1;
      const int k0 = (t + 1) * BK;
#pragma unroll
      for (int i = 0; i < 4; ++i)
        gld_lds16(gA + (int64_t)i * 32 * K + k0, lA + nb * BM * BK + i * 32 * BK);
#pragma unroll
      for (int i = 0; i < 4; ++i)
        gld_lds16(gB + (int64_t)i * 32 * K + k0, lB + nb * BM * BK + i * 32 * BK);
    }
    const u16* as = As[cur];
    const u16* bs = Bs[cur];
#pragma unroll
    for (int kk = 0; kk < 2; ++kk) {
      short8 af[4], bf[4];
#pragma unroll
      for (int m = 0; m < 4; ++m)
        af[m] = *(const short8*)&as[(wr * 64 + m * 16 + la16) * BK + kk * 32 + kg];
#pragma unroll
      for (int n = 0; n < 4; ++n)
        bf[n] = *(const short8*)&bs[(wc * 64 + n * 16 + la16) * BK + kk * 32 + kg];
#pragma unroll
      for (int m = 0; m < 4; ++m)
#pragma unroll
        for (int n = 0; n < 4; ++n)
          mfma16x16x32(acc[m][n], af[m], bf[n]);
    }
    __syncthreads();  // drains this iter's prefetch (overlapped w/ compute)
    cur ^= 1;
  }
  asm volatile("s_nop 7\n\ts_nop 7");  // MFMA->VALU hazard guard

  const int r0 = brow + wr * 64 + (lane >> 4) * 4;
  const int c0 = bcol + wc * 64 + la16;
  const int64_t b512 = (int64_t)b * 512;

  if (EPI == 4) {
    float* Cb = (float*)Cptr + (int64_t)b * Cbs;
    const float* xb = xres + (int64_t)b * Cbs;
#pragma unroll
    for (int m = 0; m < 4; ++m) {
#pragma unroll
      for (int r = 0; r < 4; ++r) {
        const int row = r0 + m * 16 + r;
        const float scl = v1[row], shf = v2[b512 + row];
#pragma unroll
        for (int n = 0; n < 4; ++n) {
          const int col = c0 + n * 16;
          Cb[(int64_t)row * N + col] = acc[m][n][r] * scl + shf + xb[(int64_t)row * N + col];
        }
      }
    }
  } else {
    u16* Cb = (u16*)Cptr + (int64_t)b * Cbs;
#pragma unroll
    for (int m = 0; m < 4; ++m) {
#pragma unroll
      for (int r = 0; r < 4; ++r) {
        const int row = r0 + m * 16 + r;
        float a1 = 0.f, a3 = 0.f;
        if (EPI == 6) { a1 = v1[b512 + row]; a3 = v3[row]; }
#pragma unroll
        for (int n = 0; n < 4; ++n) {
          const int col = c0 + n * 16;
          float v = acc[m][n][r];
          if (EPI == 6) v += a1 * v2[col] + a3 * v4[b512 + col];
          Cb[(int64_t)row * N + col] = f2bf(v);
        }
      }
    }
  }
}

// ---- f32 row -> bf16 row + row-sum for BOTH x and x_h (grid.y selects) ----
__global__ void cvt_row2(const float* __restrict__ x, const float* __restrict__ xh,
                         u16* __restrict__ xB, u16* __restrict__ xhB,
                         float* __restrict__ rx, float* __restrict__ rxh) {
  const int64_t row = blockIdx.x;
  const float* in = blockIdx.y ? xh : x;
  u16* out = blockIdx.y ? xhB : xB;
  float* rs = blockIdx.y ? rxh : rx;
  const float4* ib = (const float4*)(in + row * 1152);
  U16x4* ob = (U16x4*)(out + row * 1152);
  float s = 0.f;
  for (int i = threadIdx.x; i < 288; i += 256) {
    float4 v = ib[i];
    s += v.x + v.y + v.z + v.w;
    U16x4 o = {f2bf(v.x), f2bf(v.y), f2bf(v.z), f2bf(v.w)};
    ob[i] = o;
  }
  for (int off = 32; off; off >>= 1) s += __shfl_down(s, off);
  __shared__ float red[4];
  if ((threadIdx.x & 63) == 0) red[threadIdx.x >> 6] = s;
  __syncthreads();
  if (threadIdx.x == 0) rs[row] = red[0] + red[1] + red[2] + red[3];
}

// ---- bf16 [C][N] -> bf16 [N][C] per batch ----
__global__ void transpose_bf(const u16* __restrict__ in, u16* __restrict__ out,
                             int C, int N) {
  __shared__ u16 t[32][36];
  const int b = blockIdx.z;
  const u16* ib = in + (int64_t)b * C * N;
  u16* ob = out + (int64_t)b * C * N;
  const int n0 = blockIdx.x * 32, c0 = blockIdx.y * 32;
  const int tr = threadIdx.x >> 3, tc = (threadIdx.x & 7) * 4;
  U16x4 v = *(const U16x4*)&ib[(int64_t)(c0 + tr) * N + n0 + tc];
  t[tr][tc] = v.x; t[tr][tc + 1] = v.y; t[tr][tc + 2] = v.z; t[tr][tc + 3] = v.w;
  __syncthreads();
  U16x4 o = {t[tc][tr], t[tc + 1][tr], t[tc + 2][tr], t[tc + 3][tr]};
  *(U16x4*)&ob[(int64_t)(n0 + tr) * C + c0 + tc] = o;
}

// ---- 4x fused 512x512 f32 -> bf16 transpose (blockIdx.z selects weight) ----
__global__ void transpose_cvt4(const float* __restrict__ s0, const float* __restrict__ s1,
                               const float* __restrict__ s2, const float* __restrict__ s3,
                               u16* __restrict__ d0, u16* __restrict__ d1,
                               u16* __restrict__ d2, u16* __restrict__ d3) {
  const int z = blockIdx.z;
  const float* in = z == 0 ? s0 : z == 1 ? s1 : z == 2 ? s2 : s3;
  u16* out = z == 0 ? d0 : z == 1 ? d1 : z == 2 ? d2 : d3;
  __shared__ float t[32][33];
  const int n0 = blockIdx.x * 32, c0 = blockIdx.y * 32;
  const int tr = threadIdx.x >> 3, tc = (threadIdx.x & 7) * 4;
  const float4 v = *(const float4*)&in[(int64_t)(c0 + tr) * 512 + n0 + tc];
  t[tr][tc] = v.x; t[tr][tc + 1] = v.y; t[tr][tc + 2] = v.z; t[tr][tc + 3] = v.w;
  __syncthreads();
  U16x4 o;
  o.x = f2bf(t[tc][tr]); o.y = f2bf(t[tc + 1][tr]);
  o.z = f2bf(t[tc + 2][tr]); o.w = f2bf(t[tc + 3][tr]);
  *(U16x4*)&out[(int64_t)(n0 + tr) * 512 + c0 + tc] = o;
}

// ---- f32 -> bf16 elementwise ----
__global__ void cvt_kernel(const float* __restrict__ in, u16* __restrict__ out, int n4) {
  const int i = blockIdx.x * 256 + threadIdx.x;
  if (i < n4) {
    const float4 v = ((const float4*)in)[i];
    U16x4 o = {f2bf(v.x), f2bf(v.y), f2bf(v.z), f2bf(v.w)};
    ((U16x4*)out)[i] = o;
  }
}

// ---- batch-independent small vectors + BN prep (all coalesced) ----
__global__ void k_statics(const float* __restrict__ Wp, const u16* __restrict__ WwT,
                          const float* __restrict__ Wg,
                          const float* __restrict__ bg, const float* __restrict__ bt,
                          const float* __restrict__ bp, const float* __restrict__ bw,
                          const float* __restrict__ gamma, const float* __restrict__ beta,
                          const float* __restrict__ mean, const float* __restrict__ var,
                          float* __restrict__ h1, float* __restrict__ w1,
                          float* __restrict__ c2, float* __restrict__ s2,
                          float* __restrict__ scale, float* __restrict__ sc2,
                          float* __restrict__ shift0) {
  const int gid = blockIdx.x * 64 + threadIdx.x;
  if (gid < 512) {                    // h1[j] = sum_k Wp[k,j]*bg[k]  (coalesced)
    float s = 0;
    for (int k = 0; k < 512; ++k) s += Wp[k * 512 + gid] * bg[k];
    h1[gid] = s;
  } else if (gid < 1024) {            // w1[c] = sum_k Ww[c,k]*bt[k] via WwT (coalesced)
    const int c = gid - 512;
    float s = 0;
    for (int k = 0; k < 512; ++k) s += bf2f(WwT[k * 512 + c]) * bt[k];
    w1[c] = s;
  } else if (gid < 1536) {            // c2[e] = sum_k Wg[k,e]*bp[k]  (coalesced)
    const int e = gid - 1024;
    float s = 0;
    for (int k = 0; k < 512; ++k) s += Wg[k * 512 + e] * bp[k];
    c2[e] = s;
  } else if (gid < 2048) {            // BN prep
    const int c = gid - 1536;
    const float sc = gamma[c] * rsqrtf(var[c] + 1e-5f);
    scale[c] = sc;
    sc2[c] = sc * (1.0f / 512.0f);
    shift0[c] = (bw[c] - mean[c]) * sc + beta[c];
  } else {                            // s2 = bp . bg
    const int l = gid - 2048;
    float p = 0;
    for (int k = l; k < 512; k += 64) p += bp[k] * bg[k];
    for (int off = 32; off; off >>= 1) p += __shfl_down(p, off);
    if (l == 0) s2[0] = p;
  }
}

// ---- fused per-batch: sigphi,tau2 then c1,w2,s1 (one block = one batch) ----
__global__ void k_vecs(const u16* __restrict__ WpT, const u16* __restrict__ WtT,
                       const u16* __restrict__ WwT, const float* __restrict__ Wg,
                       const float* __restrict__ bt, const float* __restrict__ bg,
                       const float* __restrict__ rx, const float* __restrict__ rxh,
                       float* __restrict__ sigphi, float* __restrict__ tau2,
                       float* __restrict__ c1, float* __restrict__ w2,
                       float* __restrict__ s1) {
  __shared__ float rxl[512], rxhl[512], spl[512], tal[512];
  __shared__ float red[8];
  const int bb = blockIdx.x, t = threadIdx.x;
  rxl[t] = rx[bb * 512 + t];
  rxhl[t] = rxh[bb * 512 + t];
  __syncthreads();
  float sp = 0, ta = 0;
  for (int d = 0; d < 512; ++d) {
    sp += bf2f(WpT[d * 512 + t]) * rxhl[d];   // Wp[t,d] = WpT[d,t]
    ta += bf2f(WtT[d * 512 + t]) * rxl[d];
  }
  ta += 1152.0f * bt[t];
  spl[t] = sp; tal[t] = ta;
  sigphi[bb * 512 + t] = sp;
  tau2[bb * 512 + t] = ta;
  __syncthreads();
  float c = 0, wv = 0;
  for (int k = 0; k < 512; ++k) {
    c += Wg[k * 512 + t] * spl[k];            // Wg^T coalesced native
    wv += bf2f(WwT[k * 512 + t]) * tal[k];    // Ww[t,k] = WwT[k,t]
  }
  c1[bb * 512 + t] = c;
  w2[bb * 512 + t] = wv;
  float p = spl[t] * bg[t];
  for (int off = 32; off; off >>= 1) p += __shfl_down(p, off);
  if ((t & 63) == 0) red[t >> 6] = p;
  __syncthreads();
  if (t == 0) {
    float s = 0;
    for (int i = 0; i < 8; ++i) s += red[i];
    s1[bb] = s;
  }
}

// ---- per-batch u/v chain -> shiftv (coalesced via transposed weights) ----
__global__ void k_uv(const u16* __restrict__ MT, const float* __restrict__ h1,
                     const u16* __restrict__ WtT, const u16* __restrict__ WwT,
                     const float* __restrict__ bt, const float* __restrict__ tau2,
                     const float* __restrict__ s1, const float* __restrict__ s2,
                     const float* __restrict__ scale, const float* __restrict__ shift0,
                     float* __restrict__ shiftv) {
  __shared__ float h1l[512], m1l[512], ul[512];
  const int bb = blockIdx.x, t = threadIdx.x;
  h1l[t] = h1[t];
  __syncthreads();
  const u16* Mb = MT + (int64_t)bb * 262144;
  float acc = 0;
  for (int j = 0; j < 512; ++j) acc += bf2f(Mb[j * 512 + t]) * h1l[j];
  m1l[t] = acc;
  __syncthreads();
  float u = 0;
  for (int d = 0; d < 512; ++d) u += bf2f(WtT[d * 512 + t]) * m1l[d];
  u = (u + bt[t] * s1[bb] + tau2[bb * 512 + t] * s2[0]) * (1.0f / 512.0f);
  ul[t] = u;
  __syncthreads();
  float v = 0;
  for (int a = 0; a < 512; ++a) v += bf2f(WwT[a * 512 + t]) * ul[a];
  shiftv[bb * 512 + t] = v * scale[t] + shift0[t];
}

extern "C" void kernel_launch(void* const* d_in, const int* in_sizes, int n_in,
                              void* d_out, int out_size, void* d_ws, size_t ws_size,
                              hipStream_t stream) {
  const float* x     = (const float*)d_in[0];
  const float* x_h   = (const float*)d_in[1];
  const float* Wg    = (const float*)d_in[2];
  const float* bg    = (const float*)d_in[3];
  const float* Wt    = (const float*)d_in[4];
  const float* bt    = (const float*)d_in[5];
  const float* Wp    = (const float*)d_in[6];
  const float* bp    = (const float*)d_in[7];
  const float* Ww    = (const float*)d_in[8];
  const float* bw    = (const float*)d_in[9];
  const float* gamma = (const float*)d_in[10];
  const float* beta  = (const float*)d_in[11];
  const float* rmean = (const float*)d_in[12];
  const float* rvar  = (const float*)d_in[13];
  float* out = (float*)d_out;

  const int Bsz = 32, D = 512, N = 1152;
  const int64_t DN = (int64_t)D * N;   // 589824
  const int64_t DD = (int64_t)D * D;   // 262144

  char* ws = (char*)d_ws;
  const size_t KB = 1024, MB = 1048576;
  // weight pairs placed ADJACENT so the Wa/WbT GEMMs run as one z=2 dispatch
  u16* WtT  = (u16*)(ws + 0);            // pair B: [WtT, WpT]
  u16* WpT  = (u16*)(ws + 512 * KB);
  u16* WwB  = (u16*)(ws + 1 * MB);       // pair A: [WwB, WgT]
  u16* WgT  = (u16*)(ws + 1 * MB + 512 * KB);
  u16* WaB  = (u16*)(ws + 2 * MB);       // pair C: [Wa, WbT]
  u16* WbTB = (u16*)(ws + 2 * MB + 512 * KB);
  u16* WwT  = (u16*)(ws + 3 * MB);
  float* rx     = (float*)(ws + 3 * MB + 512 * KB);
  float* rxh    = (float*)(ws + 3 * MB + 576 * KB);
  float* sigphi = (float*)(ws + 3 * MB + 640 * KB);
  float* tau2   = (float*)(ws + 3 * MB + 704 * KB);
  float* c1     = (float*)(ws + 3 * MB + 768 * KB);
  float* w2     = (float*)(ws + 3 * MB + 832 * KB);
  float* shiftv = (float*)(ws + 3 * MB + 896 * KB);
  float* h1     = (float*)(ws + 3 * MB + 960 * KB);
  float* w1     = (float*)(ws + 3 * MB + 962 * KB);
  float* c2     = (float*)(ws + 3 * MB + 964 * KB);
  float* scale  = (float*)(ws + 3 * MB + 966 * KB);
  float* sc2    = (float*)(ws + 3 * MB + 968 * KB);
  float* shift0 = (float*)(ws + 3 * MB + 970 * KB);
  float* s1     = (float*)(ws + 3 * MB + 972 * KB);
  float* s2     = (float*)(ws + 3 * MB + 974 * KB);
  u16* xB  = (u16*)(ws + 4 * MB);                  // 36 MB
  u16* xhB = (u16*)(ws + 40 * MB);                 // 36 MB
  u16* xhT = (u16*)(ws + 76 * MB);                 // 36 MB
  u16* SD1 = (u16*)(ws + 112 * MB);                // 17 MB (MT -> Q)
  u16* SD2 = (u16*)(ws + 130 * MB);                // 17 MB (R)

  // --- prep ---
  cvt_row2<<<dim3(Bsz * D, 2), 256, 0, stream>>>(x, x_h, xB, xhB, rx, rxh);
  transpose_bf<<<dim3(N / 32, D / 32, Bsz), 256, 0, stream>>>(xhB, xhT, D, N);
  transpose_cvt4<<<dim3(16, 16, 4), 256, 0, stream>>>(Wt, Wp, Wg, Ww, WtT, WpT, WgT, WwT);
  cvt_kernel<<<dim3(D * D / 4 / 256), 256, 0, stream>>>(Ww, WwB, D * D / 4);
  k_statics<<<dim3(33), 64, 0, stream>>>(Wp, WwT, Wg, bg, bt, bp, bw, gamma, beta,
                                         rmean, rvar, h1, w1, c2, s2, scale, sc2, shift0);
  k_vecs<<<dim3(Bsz), 512, 0, stream>>>(WpT, WtT, WwT, Wg, bt, bg, rx, rxh,
                                        sigphi, tau2, c1, w2, s1);
  // Wa = Ww*Wt (b=0) ; WbT[e,j] = sum_k Wg[k,e]Wp[k,j] (b=1) — one dispatch
  gemm_abt<0><<<dim3(4, 4, 2), 256, 0, stream>>>(
      WwB, DD, WtT, DD, WaB, DD, D, D, D, nullptr, nullptr, nullptr, nullptr, nullptr);

  // --- main chain ---
  // G1: MT[j,i] = sum_n x_h[j,n] x[i,n]
  gemm_abt<0><<<dim3(4, 4, Bsz), 256, 0, stream>>>(
      xhB, DN, xB, DN, SD1, DD, D, D, N, nullptr, nullptr, nullptr, nullptr, nullptr);
  // shiftv (reads MT)
  k_uv<<<dim3(Bsz), 512, 0, stream>>>(SD1, h1, WtT, WwT, bt, tau2, s1, s2,
                                      scale, shift0, shiftv);
  // G2: R[p,j] = sum_i Wa[p,i] MT[j,i]
  gemm_abt<0><<<dim3(4, 4, Bsz), 256, 0, stream>>>(
      WaB, 0, SD1, DD, SD2, DD, D, D, D, nullptr, nullptr, nullptr, nullptr, nullptr);
  // G3: Q[p,e] = sum_j R[p,j] WbT[e,j] + rank-2 bias correction
  gemm_abt<6><<<dim3(4, 4, Bsz), 256, 0, stream>>>(
      SD2, DD, WbTB, 0, SD1, DD, D, D, D, w2, c2, w1, c1, nullptr);
  // G6: out[c,n] = sc2[c]*sum_e Q[c,e] xhT[n,e] + shiftv[b,c] + x[b,c,n]
  gemm_abt<4><<<dim3(N / 128, 4, Bsz), 256, 0, stream>>>(
      SD1, DD, xhT, DN, out, DN, D, N, D, sc2, shiftv, nullptr, nullptr, x);
}